// Round 7
// baseline (213.841 us; speedup 1.0000x reference)
//
#include <hip/hip_runtime.h>
#include <hip/hip_bf16.h>

#define T_ 1024
#define N_ 8
#define D_ 1024
#define H_ 16
#define HD_ 64

typedef __attribute__((ext_vector_type(8))) short bf16x8;
typedef __attribute__((ext_vector_type(4))) float f32x4;
typedef __attribute__((ext_vector_type(16))) float f32x16;
typedef __attribute__((ext_vector_type(4))) int i32x4;
typedef __attribute__((ext_vector_type(2))) int i32x2;
typedef unsigned short u16;
typedef unsigned int u32;

#if __has_builtin(__builtin_amdgcn_exp2f)
#define EXP2F __builtin_amdgcn_exp2f
#else
#define EXP2F exp2f
#endif

__device__ __forceinline__ float bf2f(u16 u){
  union { float f; unsigned int i; } v; v.i = ((unsigned int)u) << 16; return v.f;
}
__device__ __forceinline__ u16 f2bf(float f){
  union { float f; unsigned int i; } v; v.f = f;
  unsigned int r = v.i + 0x7FFFu + ((v.i >> 16) & 1u);
  return (u16)(r >> 16);
}
__device__ __forceinline__ u16 f2bf_fast(float f){
  __hip_bfloat16 h = __float2bfloat16(f);   // RNE; compiler packs pairs into v_cvt_pk_bf16_f32
  return *reinterpret_cast<u16*>(&h);
}

// ---------------- transpose+cast Wq (D x D) -> Wqt[n][m] bf16 ----------------
__global__ __launch_bounds__(256) void k_wqt(const float* __restrict__ Wq, u16* __restrict__ Wqt){
  __shared__ float tld[64][65];
  int m0 = blockIdx.x * 64, n0 = blockIdx.y * 64;
  int col = threadIdx.x & 63, rq = threadIdx.x >> 6;
  #pragma unroll
  for (int p = 0; p < 16; ++p){
    int row = rq * 16 + p;
    tld[row][col] = Wq[(size_t)(m0 + row) * D_ + n0 + col];
  }
  __syncthreads();
  #pragma unroll
  for (int p = 0; p < 16; ++p){
    int row = rq * 16 + p;
    Wqt[(size_t)(n0 + row) * D_ + m0 + col] = f2bf(tld[col][row]);
  }
}

// ---------------- Bp[sp][h][d][e] partials of sum_m qw[m,h,e]*vw[m,h,d] (MFMA split-K) ----------------
__global__ __launch_bounds__(256) void k_bmatp(const float* __restrict__ qw, const float* __restrict__ vw,
                                               float* __restrict__ Bp){
  int h = (int)blockIdx.x >> 3, sp = (int)blockIdx.x & 7;
  int tid = threadIdx.x, lane = tid & 63, w = tid >> 6;
  int g = lane >> 4, c = lane & 15;
  __shared__ u16 Qt[64 * 72];  // [e][m] transposed, bf16
  __shared__ u16 Vt[64 * 72];  // [d][m]
  f32x4 zero = {0.f, 0.f, 0.f, 0.f};
  f32x4 acc[4];
  #pragma unroll
  for (int eb = 0; eb < 4; ++eb) acc[eb] = zero;
  int m = tid >> 2, cg = tid & 3;
  for (int mt = sp * 128; mt < sp * 128 + 128; mt += 64){
    __syncthreads();
    #pragma unroll
    for (int q = 0; q < 4; ++q){
      int e0 = cg * 16 + q * 4;
      f32x4 vq = *(const f32x4*)(qw + (size_t)(mt + m) * D_ + h * 64 + e0);
      f32x4 vv = *(const f32x4*)(vw + (size_t)(mt + m) * D_ + h * 64 + e0);
      #pragma unroll
      for (int j = 0; j < 4; ++j){
        Qt[(e0 + j) * 72 + m] = f2bf_fast(vq[j]);
        Vt[(e0 + j) * 72 + m] = f2bf_fast(vv[j]);
      }
    }
    __syncthreads();
    #pragma unroll
    for (int kk = 0; kk < 2; ++kk){
      bf16x8 av = *(const bf16x8*)&Vt[(w * 16 + c) * 72 + kk * 32 + g * 8];
      #pragma unroll
      for (int eb = 0; eb < 4; ++eb){
        bf16x8 bq = *(const bf16x8*)&Qt[(eb * 16 + c) * 72 + kk * 32 + g * 8];
        acc[eb] = __builtin_amdgcn_mfma_f32_16x16x32_bf16(av, bq, acc[eb], 0, 0, 0);
      }
    }
  }
  #pragma unroll
  for (int eb = 0; eb < 4; ++eb)
    #pragma unroll
    for (int r = 0; r < 4; ++r){
      int d = w * 16 + g * 4 + r, e = eb * 16 + c;
      Bp[(((size_t)sp * 16 + h) * 64 + d) * 64 + e] = acc[eb][r];
    }
}

// ---------------- reduce 8 partials -> Bt bf16 ----------------
__global__ __launch_bounds__(256) void k_bred(const float* __restrict__ Bp, u16* __restrict__ Bt){
  int i = blockIdx.x * 256 + threadIdx.x;   // 65536 total
  float s = 0.f;
  #pragma unroll
  for (int j = 0; j < 8; ++j) s += Bp[(size_t)j * 65536 + i];
  Bt[i] = f2bf(s * 0.125f);
}

// swizzled u16-index within a [rows][64] u16 LDS tile: XOR byte-bits 4-6 with row&7
__device__ __forceinline__ int swz(int row, int colbyte){
  return row * 64 + (((colbyte) ^ ((row & 7) << 4)) >> 1);
}

// ---------------- 128x128 bf16 MFMA GEMM, A[MxK] @ B^T (B given [N][K]) ----------------
template<int A_F32, int B_F32, int EPI>
__global__ __launch_bounds__(256) void k_gemm(const void* __restrict__ A_, const void* __restrict__ B_,
                                              void* __restrict__ Cv, const float* __restrict__ bias,
                                              int M, int N, int K){
  int nbn = N >> 7;
  int ii = (int)blockIdx.x;
  int sw = (ii & 7) * 64 + (ii >> 3);      // XCD-contiguous chunks (512 = 8*64 blocks)
  int bm = sw / nbn, bn = sw % nbn;
  int tid = threadIdx.x, lane = tid & 63, wid = tid >> 6;
  int wr = wid >> 1, wc = wid & 1, g = lane >> 4, c = lane & 15;
  __shared__ u16 As[128 * 64];
  __shared__ u16 Bs[128 * 64];
  f32x4 zero = {0.f, 0.f, 0.f, 0.f};
  f32x4 acc[4][4];
  #pragma unroll
  for (int m = 0; m < 4; ++m)
    #pragma unroll
    for (int n = 0; n < 4; ++n) acc[m][n] = zero;
  for (int kt = 0; kt < K; kt += 64){
    __syncthreads();
    #pragma unroll
    for (int p = 0; p < 4; ++p){
      int ci = tid + p * 256;
      int row = ci >> 3, c8 = ci & 7;
      int dst = swz(row, c8 * 16);
      if (A_F32){
        const float* A = (const float*)A_;
        const float* src = A + (size_t)(bm * 128 + row) * K + kt + c8 * 8;
        f32x4 v0 = *(const f32x4*)src;
        f32x4 v1 = *(const f32x4*)(src + 4);
        union { u16 u[8]; i32x4 v; } pk;
        #pragma unroll
        for (int j = 0; j < 4; ++j){ pk.u[j] = f2bf_fast(v0[j]); pk.u[4 + j] = f2bf_fast(v1[j]); }
        *(i32x4*)&As[dst] = pk.v;
      } else {
        const u16* A = (const u16*)A_;
        *(i32x4*)&As[dst] = *(const i32x4*)(A + (size_t)(bm * 128 + row) * K + kt + c8 * 8);
      }
      if (B_F32){
        const float* B = (const float*)B_;
        const float* src = B + (size_t)(bn * 128 + row) * K + kt + c8 * 8;
        f32x4 v0 = *(const f32x4*)src;
        f32x4 v1 = *(const f32x4*)(src + 4);
        union { u16 u[8]; i32x4 v; } pk;
        #pragma unroll
        for (int j = 0; j < 4; ++j){ pk.u[j] = f2bf_fast(v0[j]); pk.u[4 + j] = f2bf_fast(v1[j]); }
        *(i32x4*)&Bs[dst] = pk.v;
      } else {
        const u16* B = (const u16*)B_;
        *(i32x4*)&Bs[dst] = *(const i32x4*)(B + (size_t)(bn * 128 + row) * K + kt + c8 * 8);
      }
    }
    __syncthreads();
    #pragma unroll
    for (int kk = 0; kk < 2; ++kk){
      bf16x8 af[4], bfr[4];
      #pragma unroll
      for (int m = 0; m < 4; ++m){
        int row = wr * 64 + m * 16 + c;
        af[m] = *(const bf16x8*)&As[swz(row, kk * 64 + g * 16)];
      }
      #pragma unroll
      for (int n = 0; n < 4; ++n){
        int row = wc * 64 + n * 16 + c;
        bfr[n] = *(const bf16x8*)&Bs[swz(row, kk * 64 + g * 16)];
      }
      #pragma unroll
      for (int m = 0; m < 4; ++m)
        #pragma unroll
        for (int n = 0; n < 4; ++n)
          acc[m][n] = __builtin_amdgcn_mfma_f32_16x16x32_bf16(af[m], bfr[n], acc[m][n], 0, 0, 0);
    }
  }
  #pragma unroll
  for (int m = 0; m < 4; ++m)
    #pragma unroll
    for (int n = 0; n < 4; ++n)
      #pragma unroll
      for (int r = 0; r < 4; ++r){
        int row = bm * 128 + wr * 64 + m * 16 + g * 4 + r;
        int col = bn * 128 + wc * 64 + n * 16 + c;
        float v = acc[m][n][r];
        if (EPI == 0){
          int t = row >> 3, b = row & 7, hh = col >> 6, dd = col & 63;
          ((u16*)Cv)[(((size_t)(b * H_ + hh)) * T_ + t) * HD_ + dd] = f2bf(v);
        } else {
          ((float*)Cv)[(size_t)row * N + col] = v + bias[col];
        }
      }
}

// ---------------- u^T = B_h^T q^T per (bh, 64-t tile); also scaled q_sq. 1 wave. ----------------
__global__ __launch_bounds__(64) void k_u(const u16* __restrict__ qb, const u16* __restrict__ Bt,
                                          u16* __restrict__ ubt, float* __restrict__ qsq){
  int bh = blockIdx.x >> 4, tt = blockIdx.x & 15;
  int h = bh & 15, t0 = tt * 64;
  int lane = threadIdx.x, g = lane >> 4, c = lane & 15;
  const float QS_SCALE = 0.125f * 1.44269504088896340736f;
  bf16x8 af[4][2], bq[4][2];
  #pragma unroll
  for (int mf = 0; mf < 4; ++mf)
    #pragma unroll
    for (int kk = 0; kk < 2; ++kk)
      af[mf][kk] = *(const bf16x8*)(Bt + ((size_t)(h * 64 + mf * 16 + c)) * 64 + kk * 32 + g * 8);
  #pragma unroll
  for (int nf = 0; nf < 4; ++nf)
    #pragma unroll
    for (int kk = 0; kk < 2; ++kk)
      bq[nf][kk] = *(const bf16x8*)(qb + ((size_t)(bh * 1024 + t0 + nf * 16 + c)) * 64 + kk * 32 + g * 8);
  // q_sq from the same bf16 q; prescaled by 0.125*log2(e)
  #pragma unroll
  for (int nf = 0; nf < 4; ++nf){
    float ss = 0.f;
    #pragma unroll
    for (int kk = 0; kk < 2; ++kk)
      #pragma unroll
      for (int j = 0; j < 8; ++j){ float f = bf2f((u16)bq[nf][kk][j]); ss = fmaf(f, f, ss); }
    ss += __shfl_xor(ss, 16);
    ss += __shfl_xor(ss, 32);
    if (lane < 16) qsq[(size_t)bh * 1024 + t0 + nf * 16 + lane] = ss * QS_SCALE;
  }
  f32x4 zero = {0.f, 0.f, 0.f, 0.f};
  f32x4 acc[4][4];
  #pragma unroll
  for (int mf = 0; mf < 4; ++mf)
    #pragma unroll
    for (int nf = 0; nf < 4; ++nf) acc[mf][nf] = zero;
  #pragma unroll
  for (int kk = 0; kk < 2; ++kk)
    #pragma unroll
    for (int mf = 0; mf < 4; ++mf)
      #pragma unroll
      for (int nf = 0; nf < 4; ++nf)
        acc[mf][nf] = __builtin_amdgcn_mfma_f32_16x16x32_bf16(af[mf][kk], bq[nf][kk], acc[mf][nf], 0, 0, 0);
  #pragma unroll
  for (int mf = 0; mf < 4; ++mf)
    #pragma unroll
    for (int nf = 0; nf < 4; ++nf)
      #pragma unroll
      for (int r = 0; r < 4; ++r)
        ubt[((size_t)(bh * 64 + mf * 16 + g * 4 + r)) * 1024 + t0 + nf * 16 + c] = f2bf(acc[mf][nf][r]);
}

// ---------------- L2 attention: 1 wave per (bh, 32-t tile), no LDS, no barriers ----------------
// 32x32x16 MFMAs. Swapped QK^T: sf = mfma(K, Q) -> lane holds P[s_r][t=lane&31],
// s_r = (r&3)+8*(r>>2)+4*hi. P packed to bf16 pairs (W words); PV A-fragment built
// with 2 permlane32_swap per 16-s k-slice (T12). l is lane-local; K/U read from L2.
__global__ __launch_bounds__(64, 3) void k_attn(const u16* __restrict__ qb, const u16* __restrict__ ubt,
                                                const float* __restrict__ qsq, u16* __restrict__ obm){
  int i = (int)blockIdx.x;
  // XCD grouping: XCD (i&7) owns bh in [16*(i&7), ...+16): per-XCD set = 4 MB (L2-fit).
  int bh = ((i & 7) << 4) + (i >> 8);
  int tt = (i >> 3) & 31;
  int b = bh >> 4, h = bh & 15;
  int lane = threadIdx.x;
  int lo = lane & 31, hi = lane >> 5;
  const float C1 = 0.25f * 1.44269504088896340736f;
  int t0 = tt * 32;
  const u16* qbh = qb + (size_t)bh * 65536;    // [t][64]
  const u16* ubh = ubt + (size_t)bh * 65536;   // [e][1024]
  const float* qsb = qsq + (size_t)bh * 1024;
  // Q B-fragment (col=t=lo, k=d): 4 K=16 slices
  bf16x8 qB[4];
  #pragma unroll
  for (int kd = 0; kd < 4; ++kd)
    qB[kd] = *(const bf16x8*)(qbh + (t0 + lo) * 64 + kd * 16 + hi * 8);
  f32x16 o0 = {0,0,0,0,0,0,0,0,0,0,0,0,0,0,0,0};
  f32x16 o1 = {0,0,0,0,0,0,0,0,0,0,0,0,0,0,0,0};
  float l_c = 0.f;
  for (int st = 0; st < 16; ++st){
    int s0 = st * 64;
    u32 W[16];
    #pragma unroll
    for (int ts = 0; ts < 2; ++ts){
      int sb = s0 + ts * 32;
      f32x16 sf = {0,0,0,0,0,0,0,0,0,0,0,0,0,0,0,0};
      __builtin_amdgcn_s_setprio(1);
      #pragma unroll
      for (int kd = 0; kd < 4; ++kd){
        bf16x8 kA = *(const bf16x8*)(qbh + (sb + lo) * 64 + kd * 16 + hi * 8);
        sf = __builtin_amdgcn_mfma_f32_32x32x16_bf16(kA, qB[kd], sf, 0, 0, 0);
      }
      __builtin_amdgcn_s_setprio(0);
      f32x4 qs[4];
      #pragma unroll
      for (int q = 0; q < 4; ++q)
        qs[q] = *(const f32x4*)(qsb + sb + q * 8 + hi * 4);
      float p[16];
      #pragma unroll
      for (int r = 0; r < 16; ++r)
        p[r] = EXP2F(fmaf(sf[r], C1, -qs[r >> 2][r & 3]));
      float sA = ((p[0] + p[1]) + (p[2] + p[3])) + ((p[4] + p[5]) + (p[6] + p[7]));
      float sB = ((p[8] + p[9]) + (p[10] + p[11])) + ((p[12] + p[13]) + (p[14] + p[15]));
      l_c += sA + sB;
      #pragma unroll
      for (int q = 0; q < 8; ++q)
        W[ts * 8 + q] = ((u32)f2bf_fast(p[2 * q + 1]) << 16) | (u32)f2bf_fast(p[2 * q]);
    }
    // PV: per k-slice m (16 s), A-frag from 2 permlane32_swap; B = U rows from L2
    #pragma unroll
    for (int m = 0; m < 4; ++m){
      int base = (m >> 1) * 8 + (m & 1) * 4;
      i32x2 sw0 = __builtin_amdgcn_permlane32_swap((int)W[base + 0], (int)W[base + 2], false, false);
      i32x2 sw1 = __builtin_amdgcn_permlane32_swap((int)W[base + 1], (int)W[base + 3], false, false);
      union { u32 w[4]; bf16x8 v; } pa;
      pa.w[0] = (u32)sw0[0]; pa.w[1] = (u32)sw1[0]; pa.w[2] = (u32)sw0[1]; pa.w[3] = (u32)sw1[1];
      bf16x8 u0 = *(const bf16x8*)(ubh + (size_t)(lo) * 1024 + s0 + m * 16 + hi * 8);
      bf16x8 u1 = *(const bf16x8*)(ubh + (size_t)(32 + lo) * 1024 + s0 + m * 16 + hi * 8);
      __builtin_amdgcn_s_setprio(1);
      o0 = __builtin_amdgcn_mfma_f32_32x32x16_bf16(pa.v, u0, o0, 0, 0, 0);
      o1 = __builtin_amdgcn_mfma_f32_32x32x16_bf16(pa.v, u1, o1, 0, 0, 0);
      __builtin_amdgcn_s_setprio(0);
    }
  }
  // l: combine the two hi-halves; lane j then holds l for t = j&31
  l_c += __shfl_xor(l_c, 32);
  float inv = 1.0f / l_c;
  #pragma unroll
  for (int r = 0; r < 16; ++r){
    int tr = (r & 3) + 8 * (r >> 2) + 4 * hi;
    float invr = __shfl(inv, tr);
    size_t rowb = ((size_t)((t0 + tr) * 8 + b)) * 1024 + h * 64;
    obm[rowb + lo] = f2bf(o0[r] * invr);
    obm[rowb + 32 + lo] = f2bf(o1[r] * invr);
  }
}

extern "C" void kernel_launch(void* const* d_in, const int* in_sizes, int n_in,
                              void* d_out, int out_size, void* d_ws, size_t ws_size,
                              hipStream_t stream) {
  const float* x   = (const float*)d_in[0];
  const float* qw  = (const float*)d_in[1];
  const float* vw  = (const float*)d_in[2];
  const float* ow  = (const float*)d_in[3];
  const float* ob_bias = (const float*)d_in[4];
  float* out = (float*)d_out;

  // d_out (32 MiB) doubles as scratch:
  //  - Bp partials (2 MiB) live at d_out front, consumed by k_bred before gemm1 writes qb there
  //  - qb (16 MiB) + ubt (16 MiB) fill it afterwards; all dead before gemm2 writes `out`.
  float* Bp = (float*)d_out;
  u16* qb  = (u16*)d_out;                                     // [bh][t][d]  16 MiB
  u16* ubt = (u16*)((char*)d_out + (size_t)16 * 1024 * 1024); // [bh][d][t]  16 MiB

  char* ws = (char*)d_ws;
  size_t off = 0;
  auto alloc = [&](size_t bytes) -> void* {
    void* p = ws + off;
    off += (bytes + 255) & ~(size_t)255;
    return p;
  };
  u16*   wqt = (u16*)  alloc((size_t)1024 * 1024 * 2);   // Wq^T bf16 [n][m]   2 MiB
  u16*   obm = (u16*)  alloc((size_t)8192 * 1024 * 2);   // attn out bf16     16 MiB
  float* qsq = (float*)alloc((size_t)128 * 1024 * 4);    // scaled |q|^2     0.5 MiB
  u16*   Bt  = (u16*)  alloc((size_t)16 * 64 * 64 * 2);  // B_h^T bf16      0.125 MiB

  k_bmatp<<<128, 256, 0, stream>>>(qw, vw, Bp);
  k_bred<<<256, 256, 0, stream>>>(Bp, Bt);
  k_wqt<<<dim3(16, 16), 256, 0, stream>>>(qw, wqt);
  // GEMM1: q = x @ Wq  (A = x f32 cast-on-stage, B = Wq^T bf16) -> qb scatter
  k_gemm<1, 0, 0><<<512, 256, 0, stream>>>(x, wqt, qb, nullptr, 8192, 1024, 1024);
  k_u<<<2048, 64, 0, stream>>>(qb, Bt, ubt, qsq);
  k_attn<<<4096, 64, 0, stream>>>(qb, ubt, qsq, obm);
  // GEMM2: out = obm @ out_w^T + b  (A = obm bf16, B = out_w f32 cast-on-stage)
  k_gemm<0, 1, 1><<<512, 256, 0, stream>>>(obm, ow, out, ob_bias, 8192, 1024, 1024);
}

// Round 8
// 140.858 us; speedup vs baseline: 1.5181x; 1.5181x over previous
//
#include <hip/hip_runtime.h>
#include <hip/hip_bf16.h>

#define T_ 1024
#define N_ 8
#define D_ 1024
#define H_ 16
#define HD_ 64

typedef __attribute__((ext_vector_type(8))) short bf16x8;
typedef __attribute__((ext_vector_type(4))) float f32x4;
typedef __attribute__((ext_vector_type(16))) float f32x16;
typedef __attribute__((ext_vector_type(4))) int i32x4;
typedef __attribute__((ext_vector_type(2))) int i32x2;
typedef unsigned short u16;
typedef unsigned int u32;

__device__ __forceinline__ float bf2f(u16 u){
  union { float f; unsigned int i; } v; v.i = ((unsigned int)u) << 16; return v.f;
}
__device__ __forceinline__ u16 f2bf(float f){
  union { float f; unsigned int i; } v; v.f = f;
  unsigned int r = v.i + 0x7FFFu + ((v.i >> 16) & 1u);
  return (u16)(r >> 16);
}
__device__ __forceinline__ u16 f2bf_fast(float f){
  __hip_bfloat16 h = __float2bfloat16(f);   // RNE; compiler packs pairs into v_cvt_pk_bf16_f32
  return *reinterpret_cast<u16*>(&h);
}
// raw v_exp_f32: args are well inside normal range (p<=e^15), skip libm fixup tail
__device__ __forceinline__ float exp2_raw(float x){
  float r;
  asm("v_exp_f32 %0, %1" : "=v"(r) : "v"(x));
  return r;
}

// ---------------- transpose+cast Wq (D x D) -> Wqt[n][m] bf16 ----------------
__global__ __launch_bounds__(256) void k_wqt(const float* __restrict__ Wq, u16* __restrict__ Wqt){
  __shared__ float tld[64][65];
  int m0 = blockIdx.x * 64, n0 = blockIdx.y * 64;
  int col = threadIdx.x & 63, rq = threadIdx.x >> 6;
  #pragma unroll
  for (int p = 0; p < 16; ++p){
    int row = rq * 16 + p;
    tld[row][col] = Wq[(size_t)(m0 + row) * D_ + n0 + col];
  }
  __syncthreads();
  #pragma unroll
  for (int p = 0; p < 16; ++p){
    int row = rq * 16 + p;
    Wqt[(size_t)(n0 + row) * D_ + m0 + col] = f2bf(tld[col][row]);
  }
}

// ---------------- Bp[sp][h][d][e] partials of sum_m qw[m,h,e]*vw[m,h,d] (MFMA split-K) ----------------
__global__ __launch_bounds__(256) void k_bmatp(const float* __restrict__ qw, const float* __restrict__ vw,
                                               float* __restrict__ Bp){
  int h = (int)blockIdx.x >> 3, sp = (int)blockIdx.x & 7;
  int tid = threadIdx.x, lane = tid & 63, w = tid >> 6;
  int g = lane >> 4, c = lane & 15;
  __shared__ u16 Qt[64 * 72];  // [e][m] transposed, bf16
  __shared__ u16 Vt[64 * 72];  // [d][m]
  f32x4 zero = {0.f, 0.f, 0.f, 0.f};
  f32x4 acc[4];
  #pragma unroll
  for (int eb = 0; eb < 4; ++eb) acc[eb] = zero;
  int m = tid >> 2, cg = tid & 3;
  for (int mt = sp * 128; mt < sp * 128 + 128; mt += 64){
    __syncthreads();
    #pragma unroll
    for (int q = 0; q < 4; ++q){
      int e0 = cg * 16 + q * 4;
      f32x4 vq = *(const f32x4*)(qw + (size_t)(mt + m) * D_ + h * 64 + e0);
      f32x4 vv = *(const f32x4*)(vw + (size_t)(mt + m) * D_ + h * 64 + e0);
      #pragma unroll
      for (int j = 0; j < 4; ++j){
        Qt[(e0 + j) * 72 + m] = f2bf_fast(vq[j]);
        Vt[(e0 + j) * 72 + m] = f2bf_fast(vv[j]);
      }
    }
    __syncthreads();
    #pragma unroll
    for (int kk = 0; kk < 2; ++kk){
      bf16x8 av = *(const bf16x8*)&Vt[(w * 16 + c) * 72 + kk * 32 + g * 8];
      #pragma unroll
      for (int eb = 0; eb < 4; ++eb){
        bf16x8 bq = *(const bf16x8*)&Qt[(eb * 16 + c) * 72 + kk * 32 + g * 8];
        acc[eb] = __builtin_amdgcn_mfma_f32_16x16x32_bf16(av, bq, acc[eb], 0, 0, 0);
      }
    }
  }
  #pragma unroll
  for (int eb = 0; eb < 4; ++eb)
    #pragma unroll
    for (int r = 0; r < 4; ++r){
      int d = w * 16 + g * 4 + r, e = eb * 16 + c;
      Bp[(((size_t)sp * 16 + h) * 64 + d) * 64 + e] = acc[eb][r];
    }
}

// ---------------- reduce 8 partials -> Bt bf16 ----------------
__global__ __launch_bounds__(256) void k_bred(const float* __restrict__ Bp, u16* __restrict__ Bt){
  int i = blockIdx.x * 256 + threadIdx.x;   // 65536 total
  float s = 0.f;
  #pragma unroll
  for (int j = 0; j < 8; ++j) s += Bp[(size_t)j * 65536 + i];
  Bt[i] = f2bf(s * 0.125f);
}

// swizzled u16-index within a [rows][64] u16 LDS tile: XOR byte-bits 4-6 with row&7
__device__ __forceinline__ int swz(int row, int colbyte){
  return row * 64 + (((colbyte) ^ ((row & 7) << 4)) >> 1);
}

// ---------------- 128x128 bf16 MFMA GEMM, A[MxK] @ B^T (B given [N][K]) ----------------
template<int A_F32, int B_F32, int EPI>
__global__ __launch_bounds__(256) void k_gemm(const void* __restrict__ A_, const void* __restrict__ B_,
                                              void* __restrict__ Cv, const float* __restrict__ bias,
                                              int M, int N, int K){
  int nbn = N >> 7;
  int ii = (int)blockIdx.x;
  int sw = (ii & 7) * 64 + (ii >> 3);      // XCD-contiguous chunks (512 = 8*64 blocks)
  int bm = sw / nbn, bn = sw % nbn;
  int tid = threadIdx.x, lane = tid & 63, wid = tid >> 6;
  int wr = wid >> 1, wc = wid & 1, g = lane >> 4, c = lane & 15;
  __shared__ u16 As[128 * 64];
  __shared__ u16 Bs[128 * 64];
  f32x4 zero = {0.f, 0.f, 0.f, 0.f};
  f32x4 acc[4][4];
  #pragma unroll
  for (int m = 0; m < 4; ++m)
    #pragma unroll
    for (int n = 0; n < 4; ++n) acc[m][n] = zero;
  for (int kt = 0; kt < K; kt += 64){
    __syncthreads();
    #pragma unroll
    for (int p = 0; p < 4; ++p){
      int ci = tid + p * 256;
      int row = ci >> 3, c8 = ci & 7;
      int dst = swz(row, c8 * 16);
      if (A_F32){
        const float* A = (const float*)A_;
        const float* src = A + (size_t)(bm * 128 + row) * K + kt + c8 * 8;
        f32x4 v0 = *(const f32x4*)src;
        f32x4 v1 = *(const f32x4*)(src + 4);
        union { u16 u[8]; i32x4 v; } pk;
        #pragma unroll
        for (int j = 0; j < 4; ++j){ pk.u[j] = f2bf_fast(v0[j]); pk.u[4 + j] = f2bf_fast(v1[j]); }
        *(i32x4*)&As[dst] = pk.v;
      } else {
        const u16* A = (const u16*)A_;
        *(i32x4*)&As[dst] = *(const i32x4*)(A + (size_t)(bm * 128 + row) * K + kt + c8 * 8);
      }
      if (B_F32){
        const float* B = (const float*)B_;
        const float* src = B + (size_t)(bn * 128 + row) * K + kt + c8 * 8;
        f32x4 v0 = *(const f32x4*)src;
        f32x4 v1 = *(const f32x4*)(src + 4);
        union { u16 u[8]; i32x4 v; } pk;
        #pragma unroll
        for (int j = 0; j < 4; ++j){ pk.u[j] = f2bf_fast(v0[j]); pk.u[4 + j] = f2bf_fast(v1[j]); }
        *(i32x4*)&Bs[dst] = pk.v;
      } else {
        const u16* B = (const u16*)B_;
        *(i32x4*)&Bs[dst] = *(const i32x4*)(B + (size_t)(bn * 128 + row) * K + kt + c8 * 8);
      }
    }
    __syncthreads();
    #pragma unroll
    for (int kk = 0; kk < 2; ++kk){
      bf16x8 af[4], bfr[4];
      #pragma unroll
      for (int m = 0; m < 4; ++m){
        int row = wr * 64 + m * 16 + c;
        af[m] = *(const bf16x8*)&As[swz(row, kk * 64 + g * 16)];
      }
      #pragma unroll
      for (int n = 0; n < 4; ++n){
        int row = wc * 64 + n * 16 + c;
        bfr[n] = *(const bf16x8*)&Bs[swz(row, kk * 64 + g * 16)];
      }
      #pragma unroll
      for (int m = 0; m < 4; ++m)
        #pragma unroll
        for (int n = 0; n < 4; ++n)
          acc[m][n] = __builtin_amdgcn_mfma_f32_16x16x32_bf16(af[m], bfr[n], acc[m][n], 0, 0, 0);
    }
  }
  #pragma unroll
  for (int m = 0; m < 4; ++m)
    #pragma unroll
    for (int n = 0; n < 4; ++n)
      #pragma unroll
      for (int r = 0; r < 4; ++r){
        int row = bm * 128 + wr * 64 + m * 16 + g * 4 + r;
        int col = bn * 128 + wc * 64 + n * 16 + c;
        float v = acc[m][n][r];
        if (EPI == 0){
          int t = row >> 3, b = row & 7, hh = col >> 6, dd = col & 63;
          ((u16*)Cv)[(((size_t)(b * H_ + hh)) * T_ + t) * HD_ + dd] = f2bf(v);
        } else {
          ((float*)Cv)[(size_t)row * N + col] = v + bias[col];
        }
      }
}

// ---------------- u^T = B_h^T q^T per (bh, 64-t tile); also scaled q_sq. 1 wave. ----------------
__global__ __launch_bounds__(64) void k_u(const u16* __restrict__ qb, const u16* __restrict__ Bt,
                                          u16* __restrict__ ubt, float* __restrict__ qsq){
  int bh = blockIdx.x >> 4, tt = blockIdx.x & 15;
  int h = bh & 15, t0 = tt * 64;
  int lane = threadIdx.x, g = lane >> 4, c = lane & 15;
  const float QS_SCALE = 0.125f * 1.44269504088896340736f;
  bf16x8 af[4][2], bq[4][2];
  #pragma unroll
  for (int mf = 0; mf < 4; ++mf)
    #pragma unroll
    for (int kk = 0; kk < 2; ++kk)
      af[mf][kk] = *(const bf16x8*)(Bt + ((size_t)(h * 64 + mf * 16 + c)) * 64 + kk * 32 + g * 8);
  #pragma unroll
  for (int nf = 0; nf < 4; ++nf)
    #pragma unroll
    for (int kk = 0; kk < 2; ++kk)
      bq[nf][kk] = *(const bf16x8*)(qb + ((size_t)(bh * 1024 + t0 + nf * 16 + c)) * 64 + kk * 32 + g * 8);
  // q_sq from the same bf16 q; prescaled by 0.125*log2(e)
  #pragma unroll
  for (int nf = 0; nf < 4; ++nf){
    float ss = 0.f;
    #pragma unroll
    for (int kk = 0; kk < 2; ++kk)
      #pragma unroll
      for (int j = 0; j < 8; ++j){ float f = bf2f((u16)bq[nf][kk][j]); ss = fmaf(f, f, ss); }
    ss += __shfl_xor(ss, 16);
    ss += __shfl_xor(ss, 32);
    if (lane < 16) qsq[(size_t)bh * 1024 + t0 + nf * 16 + lane] = ss * QS_SCALE;
  }
  f32x4 zero = {0.f, 0.f, 0.f, 0.f};
  f32x4 acc[4][4];
  #pragma unroll
  for (int mf = 0; mf < 4; ++mf)
    #pragma unroll
    for (int nf = 0; nf < 4; ++nf) acc[mf][nf] = zero;
  #pragma unroll
  for (int kk = 0; kk < 2; ++kk)
    #pragma unroll
    for (int mf = 0; mf < 4; ++mf)
      #pragma unroll
      for (int nf = 0; nf < 4; ++nf)
        acc[mf][nf] = __builtin_amdgcn_mfma_f32_16x16x32_bf16(af[mf][kk], bq[nf][kk], acc[mf][nf], 0, 0, 0);
  #pragma unroll
  for (int mf = 0; mf < 4; ++mf)
    #pragma unroll
    for (int nf = 0; nf < 4; ++nf)
      #pragma unroll
      for (int r = 0; r < 4; ++r)
        ubt[((size_t)(bh * 64 + mf * 16 + g * 4 + r)) * 1024 + t0 + nf * 16 + c] = f2bf(acc[mf][nf][r]);
}

// ---------------- L2 attention: TBLK=128, 4 waves x 32 t, LDS-staged K/U, 32x32 MFMA ----------------
// K/U (64 s) staged to LDS once per round (amortized over 128 t); swapped QK^T
// sf = mfma(K, Q) -> lane holds P[s_r][t=lo], s_r=(r&3)+8*(r>>2)+4*hi. P stays
// in-register: packed to bf16 pairs, PV A-frag via 2 permlane32_swap per k-slice.
// l is lane-local (one shfl_xor(32) at end). No P LDS round-trip.
__global__ __launch_bounds__(256) void k_attn(const u16* __restrict__ qb, const u16* __restrict__ ubt,
                                              const float* __restrict__ qsq, u16* __restrict__ obm){
  int i = (int)blockIdx.x;
  // XCD grouping: XCD (i&7) owns bh in [16*(i&7), ...+16), all 8 t-tiles.
  int bh = ((i & 7) << 4) + (i >> 6);
  int tt = (i >> 3) & 7;
  int b = bh >> 4, h = bh & 15;
  int tid = threadIdx.x, w = tid >> 6, lane = tid & 63;
  int lo = lane & 31, hi = lane >> 5;
  __shared__ u16 Kl[64 * 64];
  __shared__ u16 Ul[64 * 64];
  const float C1 = 0.25f * 1.44269504088896340736f;
  int t0 = tt * 128 + w * 32;
  const u16* qbh = qb + (size_t)bh * 65536;    // [t][64]
  const u16* ubh = ubt + (size_t)bh * 65536;   // [e][1024]
  const float* qsb = qsq + (size_t)bh * 1024;
  // Q B-fragment (col=t=lo, k=d): 4 K=16 slices
  bf16x8 qB[4];
  #pragma unroll
  for (int kd = 0; kd < 4; ++kd)
    qB[kd] = *(const bf16x8*)(qbh + (t0 + lo) * 64 + kd * 16 + hi * 8);
  f32x16 o0 = {0,0,0,0,0,0,0,0,0,0,0,0,0,0,0,0};
  f32x16 o1 = {0,0,0,0,0,0,0,0,0,0,0,0,0,0,0,0};
  float l_c = 0.f;
  // staging decomposition: ci in [0,512): row=ci>>3 (64 rows), c8=ci&7 (8 x 8-u16 chunks)
  int srow = tid >> 3, sc8 = tid & 7;
  int srow2 = (tid + 256) >> 3, sc82 = tid & 7;
  int sdst1 = swz(srow, sc8 * 16), sdst2 = swz(srow2, sc82 * 16);
  // T14 prefetch: issue tile-0 loads
  i32x4 rK[2], rU[2];
  rK[0] = *(const i32x4*)(qbh + srow * 64 + sc8 * 8);
  rK[1] = *(const i32x4*)(qbh + srow2 * 64 + sc82 * 8);
  rU[0] = *(const i32x4*)(ubh + (size_t)srow * 1024 + sc8 * 8);
  rU[1] = *(const i32x4*)(ubh + (size_t)srow2 * 1024 + sc82 * 8);
  for (int st = 0; st < 16; ++st){
    int s0 = st * 64;
    if (st) __syncthreads();   // prev round's LDS reads done
    *(i32x4*)&Kl[sdst1] = rK[0];
    *(i32x4*)&Kl[sdst2] = rK[1];
    *(i32x4*)&Ul[sdst1] = rU[0];
    *(i32x4*)&Ul[sdst2] = rU[1];
    if (st < 15){
      int s1 = s0 + 64;
      rK[0] = *(const i32x4*)(qbh + (s1 + srow) * 64 + sc8 * 8);
      rK[1] = *(const i32x4*)(qbh + (s1 + srow2) * 64 + sc82 * 8);
      rU[0] = *(const i32x4*)(ubh + (size_t)srow * 1024 + s1 + sc8 * 8);
      rU[1] = *(const i32x4*)(ubh + (size_t)srow2 * 1024 + s1 + sc82 * 8);
    }
    __syncthreads();
    u32 W[16];
    #pragma unroll
    for (int ts = 0; ts < 2; ++ts){
      int sb = ts * 32;
      f32x16 sf = {0,0,0,0,0,0,0,0,0,0,0,0,0,0,0,0};
      __builtin_amdgcn_s_setprio(1);
      #pragma unroll
      for (int kd = 0; kd < 4; ++kd){
        bf16x8 kA = *(const bf16x8*)&Kl[swz(sb + lo, kd * 32 + hi * 16)];
        sf = __builtin_amdgcn_mfma_f32_32x32x16_bf16(kA, qB[kd], sf, 0, 0, 0);
      }
      __builtin_amdgcn_s_setprio(0);
      f32x4 qs[4];
      #pragma unroll
      for (int q = 0; q < 4; ++q)
        qs[q] = *(const f32x4*)(qsb + s0 + sb + q * 8 + hi * 4);
      float p[16];
      #pragma unroll
      for (int r = 0; r < 16; ++r)
        p[r] = exp2_raw(fmaf(sf[r], C1, -qs[r >> 2][r & 3]));
      float sA = ((p[0] + p[1]) + (p[2] + p[3])) + ((p[4] + p[5]) + (p[6] + p[7]));
      float sB = ((p[8] + p[9]) + (p[10] + p[11])) + ((p[12] + p[13]) + (p[14] + p[15]));
      l_c += sA + sB;
      #pragma unroll
      for (int q = 0; q < 8; ++q)
        W[ts * 8 + q] = ((u32)f2bf_fast(p[2 * q + 1]) << 16) | (u32)f2bf_fast(p[2 * q]);
    }
    // PV: per k-slice m (16 s), A-frag from 2 permlane32_swap; B = U rows from LDS
    #pragma unroll
    for (int m = 0; m < 4; ++m){
      int base = (m >> 1) * 8 + (m & 1) * 4;
      i32x2 sw0 = __builtin_amdgcn_permlane32_swap((int)W[base + 0], (int)W[base + 2], false, false);
      i32x2 sw1 = __builtin_amdgcn_permlane32_swap((int)W[base + 1], (int)W[base + 3], false, false);
      union { u32 wd[4]; bf16x8 v; } pa;
      pa.wd[0] = (u32)sw0[0]; pa.wd[1] = (u32)sw1[0]; pa.wd[2] = (u32)sw0[1]; pa.wd[3] = (u32)sw1[1];
      bf16x8 u0 = *(const bf16x8*)&Ul[swz(lo, m * 32 + hi * 16)];
      bf16x8 u1 = *(const bf16x8*)&Ul[swz(32 + lo, m * 32 + hi * 16)];
      __builtin_amdgcn_s_setprio(1);
      o0 = __builtin_amdgcn_mfma_f32_32x32x16_bf16(pa.v, u0, o0, 0, 0, 0);
      o1 = __builtin_amdgcn_mfma_f32_32x32x16_bf16(pa.v, u1, o1, 0, 0, 0);
      __builtin_amdgcn_s_setprio(0);
    }
  }
  // l: combine the two hi-halves; lane j then holds l for t = j&31
  l_c += __shfl_xor(l_c, 32);
  float inv = 1.0f / l_c;
  #pragma unroll
  for (int r = 0; r < 16; ++r){
    int tr = (r & 3) + 8 * (r >> 2) + 4 * hi;
    float invr = __shfl(inv, tr);
    size_t rowb = ((size_t)((t0 + tr) * 8 + b)) * 1024 + h * 64;
    obm[rowb + lo] = f2bf(o0[r] * invr);
    obm[rowb + 32 + lo] = f2bf(o1[r] * invr);
  }
}

extern "C" void kernel_launch(void* const* d_in, const int* in_sizes, int n_in,
                              void* d_out, int out_size, void* d_ws, size_t ws_size,
                              hipStream_t stream) {
  const float* x   = (const float*)d_in[0];
  const float* qw  = (const float*)d_in[1];
  const float* vw  = (const float*)d_in[2];
  const float* ow  = (const float*)d_in[3];
  const float* ob_bias = (const float*)d_in[4];
  float* out = (float*)d_out;

  // d_out (32 MiB) doubles as scratch:
  //  - Bp partials (2 MiB) live at d_out front, consumed by k_bred before gemm1 writes qb there
  //  - qb (16 MiB) + ubt (16 MiB) fill it afterwards; all dead before gemm2 writes `out`.
  float* Bp = (float*)d_out;
  u16* qb  = (u16*)d_out;                                     // [bh][t][d]  16 MiB
  u16* ubt = (u16*)((char*)d_out + (size_t)16 * 1024 * 1024); // [bh][d][t]  16 MiB

  char* ws = (char*)d_ws;
  size_t off = 0;
  auto alloc = [&](size_t bytes) -> void* {
    void* p = ws + off;
    off += (bytes + 255) & ~(size_t)255;
    return p;
  };
  u16*   wqt = (u16*)  alloc((size_t)1024 * 1024 * 2);   // Wq^T bf16 [n][m]   2 MiB
  u16*   obm = (u16*)  alloc((size_t)8192 * 1024 * 2);   // attn out bf16     16 MiB
  float* qsq = (float*)alloc((size_t)128 * 1024 * 4);    // scaled |q|^2     0.5 MiB
  u16*   Bt  = (u16*)  alloc((size_t)16 * 64 * 64 * 2);  // B_h^T bf16      0.125 MiB

  k_bmatp<<<128, 256, 0, stream>>>(qw, vw, Bp);
  k_bred<<<256, 256, 0, stream>>>(Bp, Bt);
  k_wqt<<<dim3(16, 16), 256, 0, stream>>>(qw, wqt);
  // GEMM1: q = x @ Wq  (A = x f32 cast-on-stage, B = Wq^T bf16) -> qb scatter
  k_gemm<1, 0, 0><<<512, 256, 0, stream>>>(x, wqt, qb, nullptr, 8192, 1024, 1024);
  k_u<<<2048, 64, 0, stream>>>(qb, Bt, ubt, qsq);
  k_attn<<<1024, 256, 0, stream>>>(qb, ubt, qsq, obm);
  // GEMM2: out = obm @ out_w^T + b  (A = obm bf16, B = out_w f32 cast-on-stage)
  k_gemm<0, 1, 1><<<512, 256, 0, stream>>>(obm, ow, out, ob_bias, 8192, 1024, 1024);
}